// Round 1
// baseline (899.107 us; speedup 1.0000x reference)
//
#include <hip/hip_runtime.h>
#include <math.h>

#define NB 8
#define NREG 64
#define DIM 1024
#define ADIM 128
#define HDIM 256

#define WCOLS 32                 // columns per D-slice
#define NSLICE (DIM / WCOLS)     // 32
#define NCHUNK 16                // row chunks
#define SEG_BLOCKS (NSLICE * NCHUNK)

// ---------------- ws layout (bytes) ----------------
// sums   f32[NREG*DIM]   @ 0        (262144)
// r      f32[NREG*DIM]   @ 262144   (262144)
// counts u32[NREG]       @ 524288   (256)
// mm     u32[4]          @ 524544   (16)  [minx,miny,maxx,maxy as orderable uints]
// scores f32[NREG]       @ 524608   (256)

__device__ __forceinline__ unsigned f2ord(float f) {
    unsigned u = __float_as_uint(f);
    return (u & 0x80000000u) ? ~u : (u | 0x80000000u);
}
__device__ __forceinline__ float ord2f(unsigned o) {
    unsigned u = (o & 0x80000000u) ? (o ^ 0x80000000u) : ~o;
    return __uint_as_float(u);
}

// K1: init workspace accumulators + seed logit with c2_b
__global__ void k_init(float* sums, unsigned* counts, unsigned* mm,
                       float* out, const float* __restrict__ c2_b) {
    int idx = blockIdx.x * blockDim.x + threadIdx.x;
    if (idx < 16384) {
        ((float4*)sums)[idx] = make_float4(0.f, 0.f, 0.f, 0.f);
    } else if (idx < 16400) {
        ((uint4*)counts)[idx - 16384] = make_uint4(0u, 0u, 0u, 0u);
    } else if (idx == 16400) {
        mm[0] = 0xFFFFFFFFu; mm[1] = 0xFFFFFFFFu;  // mins
        mm[2] = 0u;          mm[3] = 0u;           // maxs
        out[0] = c2_b[0];
    }
}

// K2: coords min/max per axis
__global__ __launch_bounds__(256) void k_minmax(const float2* __restrict__ coords,
                                                int N, unsigned* mm) {
    float mnx = 1e30f, mny = 1e30f, mxx = -1e30f, mxy = -1e30f;
    for (int i = blockIdx.x * blockDim.x + threadIdx.x; i < N;
         i += gridDim.x * blockDim.x) {
        float2 c = coords[i];
        mnx = fminf(mnx, c.x); mny = fminf(mny, c.y);
        mxx = fmaxf(mxx, c.x); mxy = fmaxf(mxy, c.y);
    }
    for (int off = 32; off; off >>= 1) {
        mnx = fminf(mnx, __shfl_xor(mnx, off));
        mny = fminf(mny, __shfl_xor(mny, off));
        mxx = fmaxf(mxx, __shfl_xor(mxx, off));
        mxy = fmaxf(mxy, __shfl_xor(mxy, off));
    }
    __shared__ float s[4][4];
    int w = threadIdx.x >> 6, lane = threadIdx.x & 63;
    if (lane == 0) { s[w][0] = mnx; s[w][1] = mny; s[w][2] = mxx; s[w][3] = mxy; }
    __syncthreads();
    if (threadIdx.x == 0) {
        for (int i = 1; i < 4; ++i) {
            s[0][0] = fminf(s[0][0], s[i][0]);
            s[0][1] = fminf(s[0][1], s[i][1]);
            s[0][2] = fmaxf(s[0][2], s[i][2]);
            s[0][3] = fmaxf(s[0][3], s[i][3]);
        }
        atomicMin(&mm[0], f2ord(s[0][0]));
        atomicMin(&mm[1], f2ord(s[0][1]));
        atomicMax(&mm[2], f2ord(s[0][2]));
        atomicMax(&mm[3], f2ord(s[0][3]));
    }
}

// K3: the big one — segment sums of x into [64][1024], plus counts (slice 0 only)
__global__ __launch_bounds__(256) void k_segsum(const float4* __restrict__ x4,
                                                const float2* __restrict__ coords,
                                                int N,
                                                const unsigned* __restrict__ mm,
                                                float* __restrict__ sums,
                                                unsigned* __restrict__ counts) {
    // LDS tile: [4 components][64 regions][8 f4-cols], region stride 9 to spread banks
    __shared__ float lsum[4 * 576];
    __shared__ unsigned lcnt[NREG];
    int t = threadIdx.x;
    for (int i = t; i < 4 * 576; i += 256) lsum[i] = 0.f;
    if (t < NREG) lcnt[t] = 0u;

    int s = blockIdx.x & (NSLICE - 1);
    int chunk = blockIdx.x >> 5;
    int rpc = (N + NCHUNK - 1) / NCHUNK;
    int row0 = chunk * rpc;
    int row1 = min(N, row0 + rpc);

    float lox = ord2f(mm[0]), loy = ord2f(mm[1]);
    float hix = ord2f(mm[2]), hiy = ord2f(mm[3]);
    float spx = fmaxf(hix - lox, 1.0f);
    float spy = fmaxf(hiy - loy, 1.0f);

    __syncthreads();

    int rl = t >> 3;       // 0..31 rows per iteration
    int i  = t & 7;        // float4 column within slice
    int c4 = s * (WCOLS / 4) + i;

    #pragma unroll 2
    for (int row = row0 + rl; row < row1; row += 32) {
        float2 c = coords[row];
        float qx = ((c.x - lox) / spx) * (float)NB;
        float qy = ((c.y - loy) / spy) * (float)NB;
        int bx = min(max((int)qx, 0), NB - 1);
        int by = min(max((int)qy, 0), NB - 1);
        int rid = by * NB + bx;
        float4 v = x4[row * (DIM / 4) + c4];
        atomicAdd(&lsum[0 * 576 + rid * 9 + i], v.x);
        atomicAdd(&lsum[1 * 576 + rid * 9 + i], v.y);
        atomicAdd(&lsum[2 * 576 + rid * 9 + i], v.z);
        atomicAdd(&lsum[3 * 576 + rid * 9 + i], v.w);
        if (s == 0 && i == 0) atomicAdd(&lcnt[rid], 1u);
    }
    __syncthreads();

    int c0 = s * WCOLS;
    for (int idx = t; idx < NREG * WCOLS; idx += 256) {
        int reg = idx >> 5;
        int c = idx & 31;
        float val = lsum[(c & 3) * 576 + reg * 9 + (c >> 2)];
        unsafeAtomicAdd(&sums[reg * DIM + c0 + c], val);
    }
    if (s == 0) {
        for (int idx = t; idx < NREG; idx += 256) atomicAdd(&counts[idx], lcnt[idx]);
    }
}

// K4: per-region mean r + gated attention score (one block per region)
__global__ __launch_bounds__(256) void k_scores(const float* __restrict__ sums,
                                                const unsigned* __restrict__ counts,
                                                const float* __restrict__ U_w,
                                                const float* __restrict__ U_b,
                                                const float* __restrict__ V_w,
                                                const float* __restrict__ V_b,
                                                const float* __restrict__ w_w,
                                                float* __restrict__ r_out,
                                                float* __restrict__ scores) {
    __shared__ float rv[DIM];
    __shared__ float sp[4];
    int reg = blockIdx.x, t = threadIdx.x;
    unsigned cnt = counts[reg];
    float den = fmaxf((float)cnt, 1.0f);
    for (int d = t; d < DIM; d += 256) {
        float v = sums[reg * DIM + d] / den;
        rv[d] = v;
        r_out[reg * DIM + d] = v;
    }
    __syncthreads();
    int w = t >> 6, lane = t & 63;
    float part = 0.f;
    for (int a = w; a < ADIM; a += 4) {
        float du = 0.f, dv = 0.f;
        const float* Ua = U_w + a * DIM;
        const float* Va = V_w + a * DIM;
        #pragma unroll
        for (int j = 0; j < 16; ++j) {
            int d = lane + j * 64;
            float rd = rv[d];
            du = fmaf(Ua[d], rd, du);
            dv = fmaf(Va[d], rd, dv);
        }
        for (int off = 32; off; off >>= 1) {
            du += __shfl_xor(du, off);
            dv += __shfl_xor(dv, off);
        }
        if (lane == 0) {
            float g = tanhf(du + U_b[a]) * (1.0f / (1.0f + expf(-(dv + V_b[a]))));
            part = fmaf(w_w[a], g, part);
        }
    }
    if (lane == 0) sp[w] = part;
    __syncthreads();
    if (t == 0) {
        float sc = sp[0] + sp[1] + sp[2] + sp[3];
        scores[reg] = (cnt > 0u) ? sc : -INFINITY;
    }
}

// K5: softmax over 64 scores -> attn, then slide = sum_r attn[r]*r[r,:]
__global__ __launch_bounds__(256) void k_attn_slide(const float* __restrict__ scores,
                                                    const float* __restrict__ r_ws,
                                                    float* __restrict__ out) {
    __shared__ float att[NREG];
    int t = threadIdx.x;
    if (t < 64) {
        float sc = scores[t];
        float m = sc;
        for (int off = 32; off; off >>= 1) m = fmaxf(m, __shfl_xor(m, off));
        float e = expf(sc - m);
        float sum = e;
        for (int off = 32; off; off >>= 1) sum += __shfl_xor(sum, off);
        float a = e / sum;
        att[t] = a;
        out[1 + DIM + t] = a;
    }
    __syncthreads();
    for (int d = t; d < DIM; d += 256) {
        float acc = 0.f;
        #pragma unroll 8
        for (int reg = 0; reg < NREG; ++reg)
            acc = fmaf(att[reg], r_ws[reg * DIM + d], acc);
        out[1 + d] = acc;
    }
}

// K6: h = relu(c1_w @ slide + c1_b); logit += c2_w . h  (4 rows per block)
__global__ __launch_bounds__(256) void k_classifier(const float* __restrict__ c1_w,
                                                    const float* __restrict__ c1_b,
                                                    const float* __restrict__ c2_w,
                                                    const float* __restrict__ slide,
                                                    float* __restrict__ out) {
    int w = threadIdx.x >> 6, lane = threadIdx.x & 63;
    int j = blockIdx.x * 4 + w;
    const float* cw = c1_w + j * DIM;
    float acc = 0.f;
    #pragma unroll
    for (int jj = 0; jj < 16; ++jj) {
        int d = lane + jj * 64;
        acc = fmaf(cw[d], slide[d], acc);
    }
    for (int off = 32; off; off >>= 1) acc += __shfl_xor(acc, off);
    __shared__ float sp[4];
    if (lane == 0) sp[w] = fmaxf(acc + c1_b[j], 0.f) * c2_w[j];
    __syncthreads();
    if (threadIdx.x == 0) unsafeAtomicAdd(&out[0], sp[0] + sp[1] + sp[2] + sp[3]);
}

extern "C" void kernel_launch(void* const* d_in, const int* in_sizes, int n_in,
                              void* d_out, int out_size, void* d_ws, size_t ws_size,
                              hipStream_t stream) {
    const float*  x      = (const float*)d_in[0];
    const float2* coords = (const float2*)d_in[1];
    const float*  U_w    = (const float*)d_in[2];
    const float*  U_b    = (const float*)d_in[3];
    const float*  V_w    = (const float*)d_in[4];
    const float*  V_b    = (const float*)d_in[5];
    const float*  w_w    = (const float*)d_in[6];
    const float*  c1_w   = (const float*)d_in[7];
    const float*  c1_b   = (const float*)d_in[8];
    const float*  c2_w   = (const float*)d_in[9];
    const float*  c2_b   = (const float*)d_in[10];
    int N = in_sizes[0] / DIM;

    float* out = (float*)d_out;
    char* ws = (char*)d_ws;
    float*    sums   = (float*)(ws + 0);
    float*    r_ws   = (float*)(ws + 262144);
    unsigned* counts = (unsigned*)(ws + 524288);
    unsigned* mm     = (unsigned*)(ws + 524544);
    float*    scores = (float*)(ws + 524608);

    hipLaunchKernelGGL(k_init, dim3(65), dim3(256), 0, stream,
                       sums, counts, mm, out, c2_b);
    hipLaunchKernelGGL(k_minmax, dim3(128), dim3(256), 0, stream, coords, N, mm);
    hipLaunchKernelGGL(k_segsum, dim3(SEG_BLOCKS), dim3(256), 0, stream,
                       (const float4*)x, coords, N, mm, sums, counts);
    hipLaunchKernelGGL(k_scores, dim3(NREG), dim3(256), 0, stream,
                       sums, counts, U_w, U_b, V_w, V_b, w_w, r_ws, scores);
    hipLaunchKernelGGL(k_attn_slide, dim3(1), dim3(256), 0, stream,
                       scores, r_ws, out);
    hipLaunchKernelGGL(k_classifier, dim3(NREG), dim3(256), 0, stream,
                       c1_w, c1_b, c2_w, out + 1, out);
}

// Round 2
// 636.947 us; speedup vs baseline: 1.4116x; 1.4116x over previous
//
#include <hip/hip_runtime.h>
#include <math.h>

#define NB 8
#define NREG 64
#define DIM 1024
#define ADIM 128
#define HDIM 256

#define WCOLS 64                 // columns per D-slice
#define NF4   (WCOLS / 4)        // 16 float4 per slice
#define NSLICE (DIM / WCOLS)     // 16
#define NCHUNK 64                // row chunks
#define SEG_BLOCKS (NSLICE * NCHUNK)  // 1024
#define LSTRIDE 17               // NF4 + 1 pad (floats)
#define LPLANE (NREG * LSTRIDE)  // 1088 floats per component plane

// ---------------- ws layout (bytes) ----------------
// sums   f32[NREG*DIM]   @ 0        (262144)
// r      f32[NREG*DIM]   @ 262144   (262144)
// counts u32[NREG]       @ 524288   (256)
// mm     u32[4]          @ 524544   (16)
// scores f32[NREG]       @ 524608   (256)
// rid    u8[N]           @ 524864   (100000)

__device__ __forceinline__ unsigned f2ord(float f) {
    unsigned u = __float_as_uint(f);
    return (u & 0x80000000u) ? ~u : (u | 0x80000000u);
}
__device__ __forceinline__ float ord2f(unsigned o) {
    unsigned u = (o & 0x80000000u) ? (o ^ 0x80000000u) : ~o;
    return __uint_as_float(u);
}

// K1: init accumulators + seed logit with c2_b
__global__ void k_init(float* sums, unsigned* counts, unsigned* mm,
                       float* scores, float* out, const float* __restrict__ c2_b) {
    int idx = blockIdx.x * blockDim.x + threadIdx.x;
    if (idx < 16384) {
        ((float4*)sums)[idx] = make_float4(0.f, 0.f, 0.f, 0.f);
    } else if (idx < 16400) {
        ((uint4*)counts)[idx - 16384] = make_uint4(0u, 0u, 0u, 0u);
    } else if (idx == 16400) {
        mm[0] = 0xFFFFFFFFu; mm[1] = 0xFFFFFFFFu;
        mm[2] = 0u;          mm[3] = 0u;
        out[0] = c2_b[0];
    } else if (idx >= 16401 && idx < 16401 + NREG) {
        scores[idx - 16401] = 0.f;
    }
}

// K2: coords min/max per axis
__global__ __launch_bounds__(256) void k_minmax(const float2* __restrict__ coords,
                                                int N, unsigned* mm) {
    float mnx = 1e30f, mny = 1e30f, mxx = -1e30f, mxy = -1e30f;
    for (int i = blockIdx.x * blockDim.x + threadIdx.x; i < N;
         i += gridDim.x * blockDim.x) {
        float2 c = coords[i];
        mnx = fminf(mnx, c.x); mny = fminf(mny, c.y);
        mxx = fmaxf(mxx, c.x); mxy = fmaxf(mxy, c.y);
    }
    for (int off = 32; off; off >>= 1) {
        mnx = fminf(mnx, __shfl_xor(mnx, off));
        mny = fminf(mny, __shfl_xor(mny, off));
        mxx = fmaxf(mxx, __shfl_xor(mxx, off));
        mxy = fmaxf(mxy, __shfl_xor(mxy, off));
    }
    __shared__ float s[4][4];
    int w = threadIdx.x >> 6, lane = threadIdx.x & 63;
    if (lane == 0) { s[w][0] = mnx; s[w][1] = mny; s[w][2] = mxx; s[w][3] = mxy; }
    __syncthreads();
    if (threadIdx.x == 0) {
        for (int i = 1; i < 4; ++i) {
            s[0][0] = fminf(s[0][0], s[i][0]);
            s[0][1] = fminf(s[0][1], s[i][1]);
            s[0][2] = fmaxf(s[0][2], s[i][2]);
            s[0][3] = fmaxf(s[0][3], s[i][3]);
        }
        atomicMin(&mm[0], f2ord(s[0][0]));
        atomicMin(&mm[1], f2ord(s[0][1]));
        atomicMax(&mm[2], f2ord(s[0][2]));
        atomicMax(&mm[3], f2ord(s[0][3]));
    }
}

// K3: region id per point (u8) + counts histogram
__global__ __launch_bounds__(256) void k_rid(const float2* __restrict__ coords,
                                             int N, const unsigned* __restrict__ mm,
                                             unsigned char* __restrict__ rid,
                                             unsigned* __restrict__ counts) {
    __shared__ unsigned lcnt[NREG];
    int t = threadIdx.x;
    if (t < NREG) lcnt[t] = 0u;
    __syncthreads();
    int i = blockIdx.x * 256 + t;
    if (i < N) {
        float lox = ord2f(mm[0]), loy = ord2f(mm[1]);
        float hix = ord2f(mm[2]), hiy = ord2f(mm[3]);
        float spx = fmaxf(hix - lox, 1.0f);
        float spy = fmaxf(hiy - loy, 1.0f);
        float2 c = coords[i];
        float qx = ((c.x - lox) / spx) * (float)NB;
        float qy = ((c.y - loy) / spy) * (float)NB;
        int bx = min(max((int)qx, 0), NB - 1);
        int by = min(max((int)qy, 0), NB - 1);
        int r = by * NB + bx;
        rid[i] = (unsigned char)r;
        atomicAdd(&lcnt[r], 1u);
    }
    __syncthreads();
    if (t < NREG) atomicAdd(&counts[t], lcnt[t]);
}

// K4: segment sums of x into [64][1024]
__global__ __launch_bounds__(256) void k_segsum(const float4* __restrict__ x4,
                                                const unsigned char* __restrict__ rid,
                                                int N,
                                                float* __restrict__ sums) {
    __shared__ float lsum[4 * LPLANE];   // 17408 B
    int t = threadIdx.x;
    for (int idx = t; idx < 4 * LPLANE; idx += 256) lsum[idx] = 0.f;

    int s = blockIdx.x & (NSLICE - 1);
    int chunk = blockIdx.x >> 4;
    int rpc = (N + NCHUNK - 1) / NCHUNK;
    int row0 = chunk * rpc;
    int row1 = min(N, row0 + rpc);
    __syncthreads();

    int rl = t >> 4;        // 0..15 row lane-group
    int i  = t & 15;        // float4 col within slice
    const float4* xp = x4 + (s * NF4 + i);

    int row = row0 + rl;
    for (; row + 48 < row1; row += 64) {
        unsigned d0 = rid[row];
        unsigned d1 = rid[row + 16];
        unsigned d2 = rid[row + 32];
        unsigned d3 = rid[row + 48];
        float4 v0 = xp[(size_t)row * (DIM / 4)];
        float4 v1 = xp[(size_t)(row + 16) * (DIM / 4)];
        float4 v2 = xp[(size_t)(row + 32) * (DIM / 4)];
        float4 v3 = xp[(size_t)(row + 48) * (DIM / 4)];
        int a0 = (int)d0 * LSTRIDE + i;
        int a1 = (int)d1 * LSTRIDE + i;
        int a2 = (int)d2 * LSTRIDE + i;
        int a3 = (int)d3 * LSTRIDE + i;
        atomicAdd(&lsum[a0], v0.x); atomicAdd(&lsum[LPLANE + a0], v0.y);
        atomicAdd(&lsum[2 * LPLANE + a0], v0.z); atomicAdd(&lsum[3 * LPLANE + a0], v0.w);
        atomicAdd(&lsum[a1], v1.x); atomicAdd(&lsum[LPLANE + a1], v1.y);
        atomicAdd(&lsum[2 * LPLANE + a1], v1.z); atomicAdd(&lsum[3 * LPLANE + a1], v1.w);
        atomicAdd(&lsum[a2], v2.x); atomicAdd(&lsum[LPLANE + a2], v2.y);
        atomicAdd(&lsum[2 * LPLANE + a2], v2.z); atomicAdd(&lsum[3 * LPLANE + a2], v2.w);
        atomicAdd(&lsum[a3], v3.x); atomicAdd(&lsum[LPLANE + a3], v3.y);
        atomicAdd(&lsum[2 * LPLANE + a3], v3.z); atomicAdd(&lsum[3 * LPLANE + a3], v3.w);
    }
    for (; row < row1; row += 16) {
        unsigned d0 = rid[row];
        float4 v0 = xp[(size_t)row * (DIM / 4)];
        int a0 = (int)d0 * LSTRIDE + i;
        atomicAdd(&lsum[a0], v0.x); atomicAdd(&lsum[LPLANE + a0], v0.y);
        atomicAdd(&lsum[2 * LPLANE + a0], v0.z); atomicAdd(&lsum[3 * LPLANE + a0], v0.w);
    }
    __syncthreads();

    int c0 = s * WCOLS;
    for (int idx = t; idx < NREG * WCOLS; idx += 256) {
        int reg = idx >> 6;
        int c = idx & 63;
        float val = lsum[(c & 3) * LPLANE + reg * LSTRIDE + (c >> 2)];
        unsafeAtomicAdd(&sums[reg * DIM + c0 + c], val);
    }
}

// K5: r = sums/count, gated attention partial scores
// grid = NREG*4: block (reg, quarter of A-dim)
__global__ __launch_bounds__(256) void k_scores(const float* __restrict__ sums,
                                                const unsigned* __restrict__ counts,
                                                const float* __restrict__ U_w,
                                                const float* __restrict__ U_b,
                                                const float* __restrict__ V_w,
                                                const float* __restrict__ V_b,
                                                const float* __restrict__ w_w,
                                                float* __restrict__ r_out,
                                                float* __restrict__ scores) {
    __shared__ float rv[DIM];
    __shared__ float sp[4];
    int reg = blockIdx.x >> 2, q = blockIdx.x & 3;
    int t = threadIdx.x;
    unsigned cnt = counts[reg];
    float den = fmaxf((float)cnt, 1.0f);
    {
        float4 sv = ((const float4*)(sums + reg * DIM))[t];
        float4 rr = make_float4(sv.x / den, sv.y / den, sv.z / den, sv.w / den);
        ((float4*)rv)[t] = rr;
        if (q == 0) ((float4*)(r_out + reg * DIM))[t] = rr;
    }
    __syncthreads();
    int w = t >> 6, lane = t & 63;
    float part = 0.f;
    int abase = q * 32;
    for (int a = abase + w; a < abase + 32; a += 4) {
        float du = 0.f, dv = 0.f;
        const float* Ua = U_w + a * DIM;
        const float* Va = V_w + a * DIM;
        #pragma unroll
        for (int j = 0; j < 16; ++j) {
            int d = lane + j * 64;
            float rd = rv[d];
            du = fmaf(Ua[d], rd, du);
            dv = fmaf(Va[d], rd, dv);
        }
        for (int off = 32; off; off >>= 1) {
            du += __shfl_xor(du, off);
            dv += __shfl_xor(dv, off);
        }
        if (lane == 0) {
            float g = tanhf(du + U_b[a]) * (1.0f / (1.0f + expf(-(dv + V_b[a]))));
            part = fmaf(w_w[a], g, part);
        }
    }
    if (lane == 0) sp[w] = part;
    __syncthreads();
    if (t == 0) unsafeAtomicAdd(&scores[reg], sp[0] + sp[1] + sp[2] + sp[3]);
}

// K6: softmax over 64 scores (redundant per block), slide = sum attn*r
// grid = 16 blocks x 64 cols each
__global__ __launch_bounds__(256) void k_attn_slide(const float* __restrict__ scores,
                                                    const unsigned* __restrict__ counts,
                                                    const float* __restrict__ r_ws,
                                                    float* __restrict__ out) {
    __shared__ float att[NREG];
    __shared__ float partial[4][64];
    int t = threadIdx.x;
    if (t < 64) {
        float sc = (counts[t] > 0u) ? scores[t] : -INFINITY;
        float m = sc;
        for (int off = 32; off; off >>= 1) m = fmaxf(m, __shfl_xor(m, off));
        float e = expf(sc - m);
        float sum = e;
        for (int off = 32; off; off >>= 1) sum += __shfl_xor(sum, off);
        float a = e / sum;
        att[t] = a;
        if (blockIdx.x == 0) out[1 + DIM + t] = a;
    }
    __syncthreads();
    int d = blockIdx.x * 64 + (t & 63);
    int rg = t >> 6;
    float acc = 0.f;
    #pragma unroll
    for (int r = 0; r < 16; ++r)
        acc = fmaf(att[rg * 16 + r], r_ws[(rg * 16 + r) * DIM + d], acc);
    partial[rg][t & 63] = acc;
    __syncthreads();
    if (t < 64)
        out[1 + blockIdx.x * 64 + t] = partial[0][t] + partial[1][t] + partial[2][t] + partial[3][t];
}

// K7: h = relu(c1_w @ slide + c1_b); logit += c2_w . h
__global__ __launch_bounds__(256) void k_classifier(const float* __restrict__ c1_w,
                                                    const float* __restrict__ c1_b,
                                                    const float* __restrict__ c2_w,
                                                    const float* __restrict__ slide,
                                                    float* __restrict__ out) {
    int w = threadIdx.x >> 6, lane = threadIdx.x & 63;
    int j = blockIdx.x * 4 + w;
    const float* cw = c1_w + j * DIM;
    float acc = 0.f;
    #pragma unroll
    for (int jj = 0; jj < 16; ++jj) {
        int d = lane + jj * 64;
        acc = fmaf(cw[d], slide[d], acc);
    }
    for (int off = 32; off; off >>= 1) acc += __shfl_xor(acc, off);
    __shared__ float sp[4];
    if (lane == 0) sp[w] = fmaxf(acc + c1_b[j], 0.f) * c2_w[j];
    __syncthreads();
    if (threadIdx.x == 0) unsafeAtomicAdd(&out[0], sp[0] + sp[1] + sp[2] + sp[3]);
}

extern "C" void kernel_launch(void* const* d_in, const int* in_sizes, int n_in,
                              void* d_out, int out_size, void* d_ws, size_t ws_size,
                              hipStream_t stream) {
    const float*  x      = (const float*)d_in[0];
    const float2* coords = (const float2*)d_in[1];
    const float*  U_w    = (const float*)d_in[2];
    const float*  U_b    = (const float*)d_in[3];
    const float*  V_w    = (const float*)d_in[4];
    const float*  V_b    = (const float*)d_in[5];
    const float*  w_w    = (const float*)d_in[6];
    const float*  c1_w   = (const float*)d_in[7];
    const float*  c1_b   = (const float*)d_in[8];
    const float*  c2_w   = (const float*)d_in[9];
    const float*  c2_b   = (const float*)d_in[10];
    int N = in_sizes[0] / DIM;

    float* out = (float*)d_out;
    char* ws = (char*)d_ws;
    float*         sums   = (float*)(ws + 0);
    float*         r_ws   = (float*)(ws + 262144);
    unsigned*      counts = (unsigned*)(ws + 524288);
    unsigned*      mm     = (unsigned*)(ws + 524544);
    float*         scores = (float*)(ws + 524608);
    unsigned char* rid    = (unsigned char*)(ws + 524864);

    hipLaunchKernelGGL(k_init, dim3(65), dim3(256), 0, stream,
                       sums, counts, mm, scores, out, c2_b);
    hipLaunchKernelGGL(k_minmax, dim3(128), dim3(256), 0, stream, coords, N, mm);
    hipLaunchKernelGGL(k_rid, dim3((N + 255) / 256), dim3(256), 0, stream,
                       coords, N, mm, rid, counts);
    hipLaunchKernelGGL(k_segsum, dim3(SEG_BLOCKS), dim3(256), 0, stream,
                       (const float4*)x, rid, N, sums);
    hipLaunchKernelGGL(k_scores, dim3(NREG * 4), dim3(256), 0, stream,
                       sums, counts, U_w, U_b, V_w, V_b, w_w, r_ws, scores);
    hipLaunchKernelGGL(k_attn_slide, dim3(16), dim3(256), 0, stream,
                       scores, counts, r_ws, out);
    hipLaunchKernelGGL(k_classifier, dim3(NREG), dim3(256), 0, stream,
                       c1_w, c1_b, c2_w, out + 1, out);
}

// Round 3
// 225.071 us; speedup vs baseline: 3.9948x; 2.8300x over previous
//
#include <hip/hip_runtime.h>
#include <math.h>

#define NB 8
#define NREG 64
#define DIM 1024
#define ADIM 128
#define HDIM 256
#define SEGB 1024   // segsum blocks

// ---------------- ws layout (bytes) ----------------
// sums   f32[65*1024]  @ 0        (266240)   row 64 = dummy for pad rows
// counts u32[64]       @ 266240   (256)
// scores f32[64]       @ 266496   (256)
// mm_max u32[2]        @ 266752   (8)    zeroed
// mm_min u32[2]        @ 266760   (8)    memset 0xFF
// base   u32[65]       @ 266768   (260)
// cursor u32[64]       @ 267040   (256)
// perm   u32[padN]     @ 267328   (<=425984)  packed (rid<<24)|idx
#define SUMS_OFF   0
#define CNT_OFF    266240
#define SCORE_OFF  266496
#define MMMAX_OFF  266752
#define MMMIN_OFF  266760
#define BASE_OFF   266768
#define CUR_OFF    267040
#define PERM_OFF   267328
#define ZERO_BYTES 266760

__device__ __forceinline__ unsigned f2ord(float f) {
    unsigned u = __float_as_uint(f);
    return (u & 0x80000000u) ? ~u : (u | 0x80000000u);
}
__device__ __forceinline__ float ord2f(unsigned o) {
    unsigned u = (o & 0x80000000u) ? (o ^ 0x80000000u) : ~o;
    return __uint_as_float(u);
}

__device__ __forceinline__ int region_of(float2 c, const unsigned* mmin, const unsigned* mmax) {
    float lox = ord2f(mmin[0]), loy = ord2f(mmin[1]);
    float hix = ord2f(mmax[0]), hiy = ord2f(mmax[1]);
    float spx = fmaxf(hix - lox, 1.0f);
    float spy = fmaxf(hiy - loy, 1.0f);
    float qx = ((c.x - lox) / spx) * (float)NB;
    float qy = ((c.y - loy) / spy) * (float)NB;
    int bx = min(max((int)qx, 0), NB - 1);
    int by = min(max((int)qy, 0), NB - 1);
    return by * NB + bx;
}

// K1: coords min/max per axis
__global__ __launch_bounds__(256) void k_minmax(const float2* __restrict__ coords,
                                                int N, unsigned* mmin, unsigned* mmax) {
    float mnx = 1e30f, mny = 1e30f, mxx = -1e30f, mxy = -1e30f;
    for (int i = blockIdx.x * blockDim.x + threadIdx.x; i < N;
         i += gridDim.x * blockDim.x) {
        float2 c = coords[i];
        mnx = fminf(mnx, c.x); mny = fminf(mny, c.y);
        mxx = fmaxf(mxx, c.x); mxy = fmaxf(mxy, c.y);
    }
    for (int off = 32; off; off >>= 1) {
        mnx = fminf(mnx, __shfl_xor(mnx, off));
        mny = fminf(mny, __shfl_xor(mny, off));
        mxx = fmaxf(mxx, __shfl_xor(mxx, off));
        mxy = fmaxf(mxy, __shfl_xor(mxy, off));
    }
    __shared__ float s[4][4];
    int w = threadIdx.x >> 6, lane = threadIdx.x & 63;
    if (lane == 0) { s[w][0] = mnx; s[w][1] = mny; s[w][2] = mxx; s[w][3] = mxy; }
    __syncthreads();
    if (threadIdx.x == 0) {
        for (int i = 1; i < 4; ++i) {
            s[0][0] = fminf(s[0][0], s[i][0]);
            s[0][1] = fminf(s[0][1], s[i][1]);
            s[0][2] = fmaxf(s[0][2], s[i][2]);
            s[0][3] = fmaxf(s[0][3], s[i][3]);
        }
        atomicMin(&mmin[0], f2ord(s[0][0]));
        atomicMin(&mmin[1], f2ord(s[0][1]));
        atomicMax(&mmax[0], f2ord(s[0][2]));
        atomicMax(&mmax[1], f2ord(s[0][3]));
    }
}

// K2: region histogram
__global__ __launch_bounds__(256) void k_hist(const float2* __restrict__ coords, int N,
                                              const unsigned* __restrict__ mmin,
                                              const unsigned* __restrict__ mmax,
                                              unsigned* __restrict__ counts) {
    __shared__ unsigned lcnt[NREG];
    int t = threadIdx.x;
    if (t < NREG) lcnt[t] = 0u;
    __syncthreads();
    int i = blockIdx.x * 256 + t;
    if (i < N) {
        int r = region_of(coords[i], mmin, mmax);
        atomicAdd(&lcnt[r], 1u);
    }
    __syncthreads();
    if (t < NREG && lcnt[t]) atomicAdd(&counts[t], lcnt[t]);
}

// K3: 1-block prefix scan -> base/cursor, pad perm tail, seed logit
__global__ __launch_bounds__(256) void k_prefix(const unsigned* __restrict__ counts,
                                                unsigned* __restrict__ base,
                                                unsigned* __restrict__ cursor,
                                                unsigned* __restrict__ perm,
                                                int N, int padN,
                                                float* out, const float* __restrict__ c2_b) {
    int t = threadIdx.x;
    if (t == 0) {
        unsigned run = 0;
        for (int i = 0; i < NREG; ++i) {
            base[i] = run; cursor[i] = run; run += counts[i];
        }
        base[NREG] = run;
        out[0] = c2_b[0];
    }
    for (int j = N + t; j < padN; j += 256) perm[j] = (64u << 24);
}

// K4: scatter - perm[pos] = (rid<<24)|i
__global__ __launch_bounds__(256) void k_scatter(const float2* __restrict__ coords, int N,
                                                 const unsigned* __restrict__ mmin,
                                                 const unsigned* __restrict__ mmax,
                                                 unsigned* __restrict__ cursor,
                                                 unsigned* __restrict__ perm) {
    __shared__ unsigned lreg[NREG];
    __shared__ unsigned gbase[NREG];
    int t = threadIdx.x;
    if (t < NREG) lreg[t] = 0u;
    __syncthreads();
    int i = blockIdx.x * 256 + t;
    int r = 0; unsigned rank = 0;
    if (i < N) {
        r = region_of(coords[i], mmin, mmax);
        rank = atomicAdd(&lreg[r], 1u);
    }
    __syncthreads();
    if (t < NREG) gbase[t] = lreg[t] ? atomicAdd(&cursor[t], lreg[t]) : 0u;
    __syncthreads();
    if (i < N) perm[gbase[r] + rank] = ((unsigned)r << 24) | (unsigned)i;
}

// K5: streaming segment sum over sorted order, register accumulation
__global__ __launch_bounds__(256) void k_segsum(const float4* __restrict__ x4,
                                                const unsigned* __restrict__ perm,
                                                int rpb,
                                                float* __restrict__ sums) {
    int t = threadIdx.x;
    int j0 = blockIdx.x * rpb;
    const uint4* p4 = (const uint4*)(perm + j0);
    float acc0 = 0.f, acc1 = 0.f, acc2 = 0.f, acc3 = 0.f;
    unsigned cur = perm[j0] >> 24;

#define FLUSH() do { float* dst = sums + (size_t)cur * DIM + 4 * t;            \
        unsafeAtomicAdd(dst + 0, acc0); unsafeAtomicAdd(dst + 1, acc1);        \
        unsafeAtomicAdd(dst + 2, acc2); unsafeAtomicAdd(dst + 3, acc3); } while (0)
#define PROC(pw, v) { unsigned r_ = (pw) >> 24;                                 \
        if (r_ != cur) { FLUSH(); acc0 = acc1 = acc2 = acc3 = 0.f; cur = r_; }  \
        acc0 += (v).x; acc1 += (v).y; acc2 += (v).z; acc3 += (v).w; }

    int iters = rpb >> 3;
    for (int it = 0; it < iters; ++it) {
        uint4 pa = p4[2 * it];
        uint4 pb = p4[2 * it + 1];
        float4 v0 = x4[(size_t)(pa.x & 0xFFFFFFu) * (DIM / 4) + t];
        float4 v1 = x4[(size_t)(pa.y & 0xFFFFFFu) * (DIM / 4) + t];
        float4 v2 = x4[(size_t)(pa.z & 0xFFFFFFu) * (DIM / 4) + t];
        float4 v3 = x4[(size_t)(pa.w & 0xFFFFFFu) * (DIM / 4) + t];
        float4 v4 = x4[(size_t)(pb.x & 0xFFFFFFu) * (DIM / 4) + t];
        float4 v5 = x4[(size_t)(pb.y & 0xFFFFFFu) * (DIM / 4) + t];
        float4 v6 = x4[(size_t)(pb.z & 0xFFFFFFu) * (DIM / 4) + t];
        float4 v7 = x4[(size_t)(pb.w & 0xFFFFFFu) * (DIM / 4) + t];
        PROC(pa.x, v0); PROC(pa.y, v1); PROC(pa.z, v2); PROC(pa.w, v3);
        PROC(pb.x, v4); PROC(pb.y, v5); PROC(pb.z, v6); PROC(pb.w, v7);
    }
    FLUSH();
#undef PROC
#undef FLUSH
}

// K6: gated attention scores; block b owns a-rows 4b..4b+3 for all regions
__global__ __launch_bounds__(256) void k_scores(const float* __restrict__ sums,
                                                const unsigned* __restrict__ counts,
                                                const float* __restrict__ U_w,
                                                const float* __restrict__ U_b,
                                                const float* __restrict__ V_w,
                                                const float* __restrict__ V_b,
                                                const float* __restrict__ w_w,
                                                float* __restrict__ scores) {
    __shared__ float Us[4 * DIM];
    __shared__ float Vs[4 * DIM];
    __shared__ float rs[DIM];
    int t = threadIdx.x;
    int a0 = blockIdx.x * 4;
    const float4* U4 = (const float4*)(U_w + (size_t)a0 * DIM);
    const float4* V4 = (const float4*)(V_w + (size_t)a0 * DIM);
    #pragma unroll
    for (int k = 0; k < 4; ++k) {
        ((float4*)Us)[t + 256 * k] = U4[t + 256 * k];
        ((float4*)Vs)[t + 256 * k] = V4[t + 256 * k];
    }
    int w = t >> 6, lane = t & 63;
    int a = a0 + w;
    float ub = U_b[a], vb = V_b[a], ww = w_w[a];

    for (int reg = 0; reg < NREG; ++reg) {
        unsigned cnt = counts[reg];
        float inv = 1.0f / fmaxf((float)cnt, 1.0f);
        float4 sv = ((const float4*)(sums + (size_t)reg * DIM))[t];
        __syncthreads();   // prior iteration's rs reads done
        ((float4*)rs)[t] = make_float4(sv.x * inv, sv.y * inv, sv.z * inv, sv.w * inv);
        __syncthreads();
        float du = 0.f, dv = 0.f;
        #pragma unroll
        for (int j = 0; j < 16; ++j) {
            int d = lane + j * 64;
            float rv = rs[d];
            du = fmaf(Us[w * DIM + d], rv, du);
            dv = fmaf(Vs[w * DIM + d], rv, dv);
        }
        for (int off = 32; off; off >>= 1) {
            du += __shfl_xor(du, off);
            dv += __shfl_xor(dv, off);
        }
        if (lane == 0) {
            float g = tanhf(du + ub) * (1.0f / (1.0f + expf(-(dv + vb))));
            unsafeAtomicAdd(&scores[reg], ww * g);
        }
    }
}

// K7: softmax over 64 scores; slide = sum_r (att[r]/den[r]) * sums[r,:]
__global__ __launch_bounds__(256) void k_attn_slide(const float* __restrict__ scores,
                                                    const unsigned* __restrict__ counts,
                                                    const float* __restrict__ sums,
                                                    float* __restrict__ out) {
    __shared__ float coef[NREG];
    __shared__ float partial[4][64];
    int t = threadIdx.x;
    if (t < 64) {
        unsigned cnt = counts[t];
        float sc = (cnt > 0u) ? scores[t] : -INFINITY;
        float m = sc;
        for (int off = 32; off; off >>= 1) m = fmaxf(m, __shfl_xor(m, off));
        float e = expf(sc - m);
        float sum = e;
        for (int off = 32; off; off >>= 1) sum += __shfl_xor(sum, off);
        float a = e / sum;
        if (blockIdx.x == 0) out[1 + DIM + t] = a;
        coef[t] = a / fmaxf((float)cnt, 1.0f);
    }
    __syncthreads();
    int lane = t & 63, rg = t >> 6;
    int d = blockIdx.x * 64 + lane;
    float acc = 0.f;
    #pragma unroll
    for (int rr = 0; rr < 16; ++rr) {
        int reg = rg * 16 + rr;
        acc = fmaf(coef[reg], sums[(size_t)reg * DIM + d], acc);
    }
    partial[rg][lane] = acc;
    __syncthreads();
    if (t < 64)
        out[1 + blockIdx.x * 64 + t] =
            partial[0][t] + partial[1][t] + partial[2][t] + partial[3][t];
}

// K8: h = relu(c1_w @ slide + c1_b); logit += c2_w . h
__global__ __launch_bounds__(256) void k_classifier(const float* __restrict__ c1_w,
                                                    const float* __restrict__ c1_b,
                                                    const float* __restrict__ c2_w,
                                                    const float* __restrict__ slide,
                                                    float* __restrict__ out) {
    int w = threadIdx.x >> 6, lane = threadIdx.x & 63;
    int j = blockIdx.x * 4 + w;
    const float* cw = c1_w + (size_t)j * DIM;
    float acc = 0.f;
    #pragma unroll
    for (int jj = 0; jj < 16; ++jj) {
        int d = lane + jj * 64;
        acc = fmaf(cw[d], slide[d], acc);
    }
    for (int off = 32; off; off >>= 1) acc += __shfl_xor(acc, off);
    __shared__ float sp[4];
    if (lane == 0) sp[w] = fmaxf(acc + c1_b[j], 0.f) * c2_w[j];
    __syncthreads();
    if (threadIdx.x == 0) unsafeAtomicAdd(&out[0], sp[0] + sp[1] + sp[2] + sp[3]);
}

extern "C" void kernel_launch(void* const* d_in, const int* in_sizes, int n_in,
                              void* d_out, int out_size, void* d_ws, size_t ws_size,
                              hipStream_t stream) {
    const float*  x      = (const float*)d_in[0];
    const float2* coords = (const float2*)d_in[1];
    const float*  U_w    = (const float*)d_in[2];
    const float*  U_b    = (const float*)d_in[3];
    const float*  V_w    = (const float*)d_in[4];
    const float*  V_b    = (const float*)d_in[5];
    const float*  w_w    = (const float*)d_in[6];
    const float*  c1_w   = (const float*)d_in[7];
    const float*  c1_b   = (const float*)d_in[8];
    const float*  c2_w   = (const float*)d_in[9];
    const float*  c2_b   = (const float*)d_in[10];
    int N = in_sizes[0] / DIM;

    float* out = (float*)d_out;
    char* ws = (char*)d_ws;
    float*    sums   = (float*)(ws + SUMS_OFF);
    unsigned* counts = (unsigned*)(ws + CNT_OFF);
    float*    scores = (float*)(ws + SCORE_OFF);
    unsigned* mmax   = (unsigned*)(ws + MMMAX_OFF);
    unsigned* mmin   = (unsigned*)(ws + MMMIN_OFF);
    unsigned* base   = (unsigned*)(ws + BASE_OFF);
    unsigned* cursor = (unsigned*)(ws + CUR_OFF);
    unsigned* perm   = (unsigned*)(ws + PERM_OFF);

    int rpb = (((N + SEGB - 1) / SEGB) + 7) & ~7;   // rows per segsum block, mult of 8
    int padN = SEGB * rpb;

    hipMemsetAsync(ws, 0, ZERO_BYTES, stream);             // sums, counts, scores, mmax
    hipMemsetAsync(ws + MMMIN_OFF, 0xFF, 8, stream);       // mmin
    hipLaunchKernelGGL(k_minmax, dim3(128), dim3(256), 0, stream, coords, N, mmin, mmax);
    hipLaunchKernelGGL(k_hist, dim3((N + 255) / 256), dim3(256), 0, stream,
                       coords, N, mmin, mmax, counts);
    hipLaunchKernelGGL(k_prefix, dim3(1), dim3(256), 0, stream,
                       counts, base, cursor, perm, N, padN, out, c2_b);
    hipLaunchKernelGGL(k_scatter, dim3((N + 255) / 256), dim3(256), 0, stream,
                       coords, N, mmin, mmax, cursor, perm);
    hipLaunchKernelGGL(k_segsum, dim3(SEGB), dim3(256), 0, stream,
                       (const float4*)x, perm, rpb, sums);
    hipLaunchKernelGGL(k_scores, dim3(ADIM / 4), dim3(256), 0, stream,
                       sums, counts, U_w, U_b, V_w, V_b, w_w, scores);
    hipLaunchKernelGGL(k_attn_slide, dim3(16), dim3(256), 0, stream,
                       scores, counts, sums, out);
    hipLaunchKernelGGL(k_classifier, dim3(NREG), dim3(256), 0, stream,
                       c1_w, c1_b, c2_w, out + 1, out);
}

// Round 5
// 198.340 us; speedup vs baseline: 4.5332x; 1.1348x over previous
//
#include <hip/hip_runtime.h>
#include <math.h>

#define NB 8
#define NREG 64
#define DIM 1024
#define ADIM 128

typedef float f4 __attribute__((ext_vector_type(4)));

// ---------------- ws layout (bytes) ----------------
// sums   f32[64*1024]  @ 0        (262144)
// cursor u32[64]       @ 262144   (256)   == counts after scatter
// scores f32[64]       @ 262400   (256)
// mmax   u32[2]        @ 262656   (8)
// mmin   u32[2]        @ 262664   (8)
// slot   u32[64*CAP]   @ 262912   (~25.6 MB)
#define SUMS_OFF  0
#define CUR_OFF   262144
#define SCORE_OFF 262400
#define MMAX_OFF  262656
#define MMIN_OFF  262664
#define SLOT_OFF  262912

__device__ __forceinline__ unsigned f2ord(float f) {
    unsigned u = __float_as_uint(f);
    return (u & 0x80000000u) ? ~u : (u | 0x80000000u);
}
__device__ __forceinline__ float ord2f(unsigned o) {
    unsigned u = (o & 0x80000000u) ? (o ^ 0x80000000u) : ~o;
    return __uint_as_float(u);
}

__device__ __forceinline__ int region_of(float2 c, const unsigned* mmin, const unsigned* mmax) {
    float lox = ord2f(mmin[0]), loy = ord2f(mmin[1]);
    float hix = ord2f(mmax[0]), hiy = ord2f(mmax[1]);
    float spx = fmaxf(hix - lox, 1.0f);
    float spy = fmaxf(hiy - loy, 1.0f);
    float qx = ((c.x - lox) / spx) * (float)NB;
    float qy = ((c.y - loy) / spy) * (float)NB;
    int bx = min(max((int)qx, 0), NB - 1);
    int by = min(max((int)qy, 0), NB - 1);
    return by * NB + bx;
}

// K1: zero accumulators, seed logit. grid 64 x 256, one float4 per thread.
__global__ __launch_bounds__(256) void k_init(float* __restrict__ sums,
                                              unsigned* __restrict__ cursor,
                                              float* __restrict__ scores,
                                              unsigned* __restrict__ mmax,
                                              unsigned* __restrict__ mmin,
                                              float* __restrict__ out,
                                              const float* __restrict__ c2_b) {
    int b = blockIdx.x, t = threadIdx.x;
    ((float4*)sums)[b * 256 + t] = make_float4(0.f, 0.f, 0.f, 0.f);
    if (b == 0) {
        if (t < NREG) { cursor[t] = 0u; scores[t] = 0.f; }
        else if (t == 64) {
            mmax[0] = 0u; mmax[1] = 0u;
            mmin[0] = 0xFFFFFFFFu; mmin[1] = 0xFFFFFFFFu;
            out[0] = c2_b[0];
        }
    }
}

// K2: coords min/max per axis
__global__ __launch_bounds__(256) void k_minmax(const float2* __restrict__ coords,
                                                int N, unsigned* mmin, unsigned* mmax) {
    float mnx = 1e30f, mny = 1e30f, mxx = -1e30f, mxy = -1e30f;
    for (int i = blockIdx.x * blockDim.x + threadIdx.x; i < N;
         i += gridDim.x * blockDim.x) {
        float2 c = coords[i];
        mnx = fminf(mnx, c.x); mny = fminf(mny, c.y);
        mxx = fmaxf(mxx, c.x); mxy = fmaxf(mxy, c.y);
    }
    for (int off = 32; off; off >>= 1) {
        mnx = fminf(mnx, __shfl_xor(mnx, off));
        mny = fminf(mny, __shfl_xor(mny, off));
        mxx = fmaxf(mxx, __shfl_xor(mxx, off));
        mxy = fmaxf(mxy, __shfl_xor(mxy, off));
    }
    __shared__ float s[4][4];
    int w = threadIdx.x >> 6, lane = threadIdx.x & 63;
    if (lane == 0) { s[w][0] = mnx; s[w][1] = mny; s[w][2] = mxx; s[w][3] = mxy; }
    __syncthreads();
    if (threadIdx.x == 0) {
        for (int i = 1; i < 4; ++i) {
            s[0][0] = fminf(s[0][0], s[i][0]);
            s[0][1] = fminf(s[0][1], s[i][1]);
            s[0][2] = fmaxf(s[0][2], s[i][2]);
            s[0][3] = fmaxf(s[0][3], s[i][3]);
        }
        atomicMin(&mmin[0], f2ord(s[0][0]));
        atomicMin(&mmin[1], f2ord(s[0][1]));
        atomicMax(&mmax[0], f2ord(s[0][2]));
        atomicMax(&mmax[1], f2ord(s[0][3]));
    }
}

// K3: direct scatter into per-region slot arrays; cursor ends as counts
__global__ __launch_bounds__(256) void k_scatter(const float2* __restrict__ coords, int N,
                                                 const unsigned* __restrict__ mmin,
                                                 const unsigned* __restrict__ mmax,
                                                 unsigned* __restrict__ cursor,
                                                 unsigned* __restrict__ slot, int cap) {
    __shared__ unsigned lreg[NREG];
    __shared__ unsigned gbase[NREG];
    int t = threadIdx.x;
    if (t < NREG) lreg[t] = 0u;
    __syncthreads();
    int i = blockIdx.x * 256 + t;
    int r = 0; unsigned rank = 0;
    if (i < N) {
        r = region_of(coords[i], mmin, mmax);
        rank = atomicAdd(&lreg[r], 1u);
    }
    __syncthreads();
    if (t < NREG) gbase[t] = lreg[t] ? atomicAdd(&cursor[t], lreg[t]) : 0u;
    __syncthreads();
    if (i < N) slot[(size_t)r * cap + gbase[r] + rank] = (unsigned)i;
}

// K4: segment sum. grid = 64 regions x 16 sub-blocks; register accumulation,
// single flush. x loads nontemporal (zero reuse).
__global__ __launch_bounds__(256) void k_segsum(const f4* __restrict__ x4,
                                                const unsigned* __restrict__ slot,
                                                const unsigned* __restrict__ cursor,
                                                int cap,
                                                float* __restrict__ sums) {
    int t = threadIdx.x;
    int r = blockIdx.x >> 4;
    int k = blockIdx.x & 15;
    int cnt = (int)cursor[r];
    int chunk = ((((cnt + 15) >> 4) + 7) & ~7);      // multiple of 8 -> aligned uint4
    int j0 = k * chunk;
    int j1 = min(cnt, j0 + chunk);
    const unsigned* sl = slot + (size_t)r * cap;

    f4 acc = (f4)(0.f);
    int j = j0;
    for (; j + 8 <= j1; j += 8) {
        uint4 ia = *(const uint4*)(sl + j);
        uint4 ib = *(const uint4*)(sl + j + 4);
        f4 v0 = __builtin_nontemporal_load(x4 + (size_t)ia.x * (DIM / 4) + t);
        f4 v1 = __builtin_nontemporal_load(x4 + (size_t)ia.y * (DIM / 4) + t);
        f4 v2 = __builtin_nontemporal_load(x4 + (size_t)ia.z * (DIM / 4) + t);
        f4 v3 = __builtin_nontemporal_load(x4 + (size_t)ia.w * (DIM / 4) + t);
        f4 v4 = __builtin_nontemporal_load(x4 + (size_t)ib.x * (DIM / 4) + t);
        f4 v5 = __builtin_nontemporal_load(x4 + (size_t)ib.y * (DIM / 4) + t);
        f4 v6 = __builtin_nontemporal_load(x4 + (size_t)ib.z * (DIM / 4) + t);
        f4 v7 = __builtin_nontemporal_load(x4 + (size_t)ib.w * (DIM / 4) + t);
        acc += v0; acc += v1; acc += v2; acc += v3;
        acc += v4; acc += v5; acc += v6; acc += v7;
    }
    for (; j < j1; ++j) {
        unsigned idx = sl[j];
        f4 v = __builtin_nontemporal_load(x4 + (size_t)idx * (DIM / 4) + t);
        acc += v;
    }
    if (j1 > j0) {
        float* dst = sums + (size_t)r * DIM + 4 * t;
        unsafeAtomicAdd(dst + 0, acc.x);
        unsafeAtomicAdd(dst + 1, acc.y);
        unsafeAtomicAdd(dst + 2, acc.z);
        unsafeAtomicAdd(dst + 3, acc.w);
    }
}

// K5: gated attention scores, barrier-free: warp w owns attention row a.
// grid = ADIM/4 = 32 blocks.
__global__ __launch_bounds__(256) void k_scores(const float* __restrict__ sums,
                                                const unsigned* __restrict__ counts,
                                                const float* __restrict__ U_w,
                                                const float* __restrict__ U_b,
                                                const float* __restrict__ V_w,
                                                const float* __restrict__ V_b,
                                                const float* __restrict__ w_w,
                                                float* __restrict__ scores) {
    __shared__ float Us[4][DIM];
    __shared__ float Vs[4][DIM];
    int t = threadIdx.x, w = t >> 6, lane = t & 63;
    int a = blockIdx.x * 4 + w;
    const float4* U4 = (const float4*)(U_w + (size_t)a * DIM);
    const float4* V4 = (const float4*)(V_w + (size_t)a * DIM);
    #pragma unroll
    for (int s = 0; s < 4; ++s) {
        ((float4*)Us[w])[s * 64 + lane] = U4[s * 64 + lane];
        ((float4*)Vs[w])[s * 64 + lane] = V4[s * 64 + lane];
    }
    float ub = U_b[a], vb = V_b[a], ww = w_w[a];
    // no __syncthreads: each warp reads only its own LDS rows
    for (int reg = 0; reg < NREG; ++reg) {
        float inv = 1.0f / fmaxf((float)counts[reg], 1.0f);
        float du = 0.f, dv = 0.f;
        #pragma unroll
        for (int s = 0; s < 4; ++s) {
            float4 sv = ((const float4*)(sums + (size_t)reg * DIM))[s * 64 + lane];
            float4 u4 = ((const float4*)Us[w])[s * 64 + lane];
            float4 v4 = ((const float4*)Vs[w])[s * 64 + lane];
            float rx = sv.x * inv, ry = sv.y * inv, rz = sv.z * inv, rw = sv.w * inv;
            du = fmaf(u4.x, rx, fmaf(u4.y, ry, fmaf(u4.z, rz, fmaf(u4.w, rw, du))));
            dv = fmaf(v4.x, rx, fmaf(v4.y, ry, fmaf(v4.z, rz, fmaf(v4.w, rw, dv))));
        }
        for (int off = 32; off; off >>= 1) {
            du += __shfl_xor(du, off);
            dv += __shfl_xor(dv, off);
        }
        if (lane == 0) {
            float g = tanhf(du + ub) * (1.0f / (1.0f + expf(-(dv + vb))));
            unsafeAtomicAdd(&scores[reg], ww * g);
        }
    }
}

// K6: softmax over 64 scores; slide = sum_r (att[r]/den[r]) * sums[r,:]
__global__ __launch_bounds__(256) void k_attn_slide(const float* __restrict__ scores,
                                                    const unsigned* __restrict__ counts,
                                                    const float* __restrict__ sums,
                                                    float* __restrict__ out) {
    __shared__ float coef[NREG];
    __shared__ float partial[4][64];
    int t = threadIdx.x;
    if (t < 64) {
        unsigned cnt = counts[t];
        float sc = (cnt > 0u) ? scores[t] : -INFINITY;
        float m = sc;
        for (int off = 32; off; off >>= 1) m = fmaxf(m, __shfl_xor(m, off));
        float e = expf(sc - m);
        float sum = e;
        for (int off = 32; off; off >>= 1) sum += __shfl_xor(sum, off);
        float a = e / sum;
        if (blockIdx.x == 0) out[1 + DIM + t] = a;
        coef[t] = a / fmaxf((float)cnt, 1.0f);
    }
    __syncthreads();
    int lane = t & 63, rg = t >> 6;
    int d = blockIdx.x * 64 + lane;
    float acc = 0.f;
    #pragma unroll
    for (int rr = 0; rr < 16; ++rr) {
        int reg = rg * 16 + rr;
        acc = fmaf(coef[reg], sums[(size_t)reg * DIM + d], acc);
    }
    partial[rg][lane] = acc;
    __syncthreads();
    if (t < 64)
        out[1 + blockIdx.x * 64 + t] =
            partial[0][t] + partial[1][t] + partial[2][t] + partial[3][t];
}

// K7: h = relu(c1_w @ slide + c1_b); logit += c2_w . h
__global__ __launch_bounds__(256) void k_classifier(const float* __restrict__ c1_w,
                                                    const float* __restrict__ c1_b,
                                                    const float* __restrict__ c2_w,
                                                    const float* __restrict__ slide,
                                                    float* __restrict__ out) {
    int w = threadIdx.x >> 6, lane = threadIdx.x & 63;
    int j = blockIdx.x * 4 + w;
    const float* cw = c1_w + (size_t)j * DIM;
    float acc = 0.f;
    #pragma unroll
    for (int jj = 0; jj < 16; ++jj) {
        int d = lane + jj * 64;
        acc = fmaf(cw[d], slide[d], acc);
    }
    for (int off = 32; off; off >>= 1) acc += __shfl_xor(acc, off);
    __shared__ float sp[4];
    if (lane == 0) sp[w] = fmaxf(acc + c1_b[j], 0.f) * c2_w[j];
    __syncthreads();
    if (threadIdx.x == 0) unsafeAtomicAdd(&out[0], sp[0] + sp[1] + sp[2] + sp[3]);
}

extern "C" void kernel_launch(void* const* d_in, const int* in_sizes, int n_in,
                              void* d_out, int out_size, void* d_ws, size_t ws_size,
                              hipStream_t stream) {
    const float*  x      = (const float*)d_in[0];
    const float2* coords = (const float2*)d_in[1];
    const float*  U_w    = (const float*)d_in[2];
    const float*  U_b    = (const float*)d_in[3];
    const float*  V_w    = (const float*)d_in[4];
    const float*  V_b    = (const float*)d_in[5];
    const float*  w_w    = (const float*)d_in[6];
    const float*  c1_w   = (const float*)d_in[7];
    const float*  c1_b   = (const float*)d_in[8];
    const float*  c2_w   = (const float*)d_in[9];
    const float*  c2_b   = (const float*)d_in[10];
    int N = in_sizes[0] / DIM;

    float* out = (float*)d_out;
    char* ws = (char*)d_ws;
    float*    sums   = (float*)(ws + SUMS_OFF);
    unsigned* cursor = (unsigned*)(ws + CUR_OFF);
    float*    scores = (float*)(ws + SCORE_OFF);
    unsigned* mmax   = (unsigned*)(ws + MMAX_OFF);
    unsigned* mmin   = (unsigned*)(ws + MMIN_OFF);
    unsigned* slot   = (unsigned*)(ws + SLOT_OFF);
    int cap = (N + 7) & ~7;

    hipLaunchKernelGGL(k_init, dim3(64), dim3(256), 0, stream,
                       sums, cursor, scores, mmax, mmin, out, c2_b);
    hipLaunchKernelGGL(k_minmax, dim3(128), dim3(256), 0, stream, coords, N, mmin, mmax);
    hipLaunchKernelGGL(k_scatter, dim3((N + 255) / 256), dim3(256), 0, stream,
                       coords, N, mmin, mmax, cursor, slot, cap);
    hipLaunchKernelGGL(k_segsum, dim3(NREG * 16), dim3(256), 0, stream,
                       (const f4*)x, slot, cursor, cap, sums);
    hipLaunchKernelGGL(k_scores, dim3(ADIM / 4), dim3(256), 0, stream,
                       sums, cursor, U_w, U_b, V_w, V_b, w_w, scores);
    hipLaunchKernelGGL(k_attn_slide, dim3(16), dim3(256), 0, stream,
                       scores, cursor, sums, out);
    hipLaunchKernelGGL(k_classifier, dim3(NREG), dim3(256), 0, stream,
                       c1_w, c1_b, c2_w, out + 1, out);
}